// Round 1
// baseline (809.960 us; speedup 1.0000x reference)
//
#include <hip/hip_runtime.h>
#include <math.h>

#define BB 8  // batch count (fixed by problem instance)

__device__ __forceinline__ float sigmoidf_(float v) {
    return 1.0f / (1.0f + __expf(-v));
}

// ---- Pass 1: column-wise sum / sumsq of edge_attr (E,2) in double ----
__global__ void ea_reduce_kernel(const float* __restrict__ ea, int E, double* __restrict__ acc) {
    __shared__ double sh[4][256];
    int tid = threadIdx.x;
    double s0 = 0, q0 = 0, s1 = 0, q1 = 0;
    for (int i = blockIdx.x * blockDim.x + tid; i < E; i += gridDim.x * blockDim.x) {
        float a = ea[2 * i];
        float b = ea[2 * i + 1];
        s0 += (double)a; q0 += (double)a * (double)a;
        s1 += (double)b; q1 += (double)b * (double)b;
    }
    sh[0][tid] = s0; sh[1][tid] = q0; sh[2][tid] = s1; sh[3][tid] = q1;
    __syncthreads();
    for (int off = 128; off > 0; off >>= 1) {
        if (tid < off) {
            sh[0][tid] += sh[0][tid + off];
            sh[1][tid] += sh[1][tid + off];
            sh[2][tid] += sh[2][tid + off];
            sh[3][tid] += sh[3][tid + off];
        }
        __syncthreads();
    }
    if (tid == 0) {
        atomicAdd(&acc[0], sh[0][0]);
        atomicAdd(&acc[1], sh[1][0]);
        atomicAdd(&acc[2], sh[2][0]);
        atomicAdd(&acc[3], sh[3][0]);
    }
}

// ---- Pass 2: finalize mean / inv_std (ddof=1) ----
__global__ void finalize_stats_kernel(const double* __restrict__ acc, int E, float* __restrict__ stats) {
    double s0 = acc[0], q0 = acc[1], s1 = acc[2], q1 = acc[3];
    double m0 = s0 / E, m1 = s1 / E;
    double v0 = (q0 - s0 * s0 / E) / (double)(E - 1);
    double v1 = (q1 - s1 * s1 / E) / (double)(E - 1);
    stats[0] = (float)m0;
    stats[1] = (float)(1.0 / sqrt(v0));
    stats[2] = (float)m1;
    stats[3] = (float)(1.0 / sqrt(v1));
}

// ---- Pass 3: per-edge MLP + fused (h @ W3) scatter into out ----
__global__ __launch_bounds__(256) void edge_kernel(
    const float* __restrict__ x, const int* __restrict__ ei,
    const float* __restrict__ ea,
    const float* __restrict__ wmean, const float* __restrict__ wstd,
    const float* __restrict__ W1, const float* __restrict__ b1,
    const float* __restrict__ W2, const float* __restrict__ b2,
    const float* __restrict__ W3,
    const float* __restrict__ stats,
    float* __restrict__ out, int N, int E)
{
    __shared__ float sW1[144], sb1[16], sW2[480], sb2[30], sW3[90];
    int tid = threadIdx.x;
    for (int i = tid; i < 144; i += 256) sW1[i] = W1[i];
    for (int i = tid; i < 480; i += 256) sW2[i] = W2[i];
    if (tid < 16) sb1[tid] = b1[tid];
    if (tid < 30) sb2[tid] = b2[tid];
    if (tid < 90) sW3[tid] = W3[tid];
    __syncthreads();

    int e = blockIdx.x * blockDim.x + tid;
    if (e >= E) return;

    int src = ei[e];
    int tgt = ei[E + e];
    float dist = ea[2 * e];
    float cdir = ea[2 * e + 1];
    float inv3d = 3.0f / dist;
    float ea0 = (dist - stats[0]) * stats[1];
    float ea1 = (cdir - stats[2]) * stats[3];
    float wm0 = wmean[0], wm1 = wmean[1];
    float wsd0 = wstd[0], wsd1 = wstd[1];

    for (int b = 0; b < BB; b++) {
        const float* xb = x + (size_t)b * N * 3;
        float s0 = xb[src * 3 + 0], s1 = xb[src * 3 + 1], s2 = xb[src * 3 + 2];
        float t0 = xb[tgt * 3 + 0], t1 = xb[tgt * 3 + 1], t2 = xb[tgt * 3 + 2];
        float speed = fmaf(s1, wsd0, wm0);
        float direc = fmaf(s2, wsd1, wm1);
        float theta = fabsf(cdir - direc);
        float ew = fmaxf(0.0f, speed * __cosf(theta) * inv3d);

        float feat[9] = {s0, s1, s2, t0, t1, t2, ea0, ea1, ew};

        float h1[16];
        #pragma unroll
        for (int j = 0; j < 16; j++) {
            float a = sb1[j];
            #pragma unroll
            for (int i = 0; i < 9; i++) a = fmaf(feat[i], sW1[i * 16 + j], a);
            h1[j] = sigmoidf_(a);
        }

        float g0 = 0.0f, g1 = 0.0f, g2 = 0.0f;
        #pragma unroll
        for (int k = 0; k < 30; k++) {
            float a = sb2[k];
            #pragma unroll
            for (int j = 0; j < 16; j++) a = fmaf(h1[j], sW2[j * 30 + k], a);
            float hk = sigmoidf_(a);
            g0 = fmaf(hk, sW3[k * 3 + 0], g0);
            g1 = fmaf(hk, sW3[k * 3 + 1], g1);
            g2 = fmaf(hk, sW3[k * 3 + 2], g2);
        }

        float* ot = out + ((size_t)b * N + tgt) * 3;
        float* os = out + ((size_t)b * N + src) * 3;
        atomicAdd(&ot[0], g0);
        atomicAdd(&ot[1], g1);
        atomicAdd(&ot[2], g2);
        atomicAdd(&os[0], -g0);
        atomicAdd(&os[1], -g1);
        atomicAdd(&os[2], -g2);
    }
}

// ---- Pass 4: out = sigmoid(out + b3) in place ----
__global__ void output_kernel(float* __restrict__ out, const float* __restrict__ b3, int total) {
    int i = blockIdx.x * blockDim.x + threadIdx.x;
    if (i < total) {
        float v = out[i] + b3[i % 3];
        out[i] = sigmoidf_(v);
    }
}

extern "C" void kernel_launch(void* const* d_in, const int* in_sizes, int n_in,
                              void* d_out, int out_size, void* d_ws, size_t ws_size,
                              hipStream_t stream) {
    const float* x     = (const float*)d_in[0];
    const int*   ei    = (const int*)d_in[1];
    const float* ea    = (const float*)d_in[2];
    const float* wmean = (const float*)d_in[3];
    const float* wstd  = (const float*)d_in[4];
    const float* W1    = (const float*)d_in[5];
    const float* b1    = (const float*)d_in[6];
    const float* W2    = (const float*)d_in[7];
    const float* b2    = (const float*)d_in[8];
    const float* W3    = (const float*)d_in[9];
    const float* b3    = (const float*)d_in[10];

    int E = in_sizes[2] / 2;        // edge_attr is (E, 2)
    int B = BB;
    int N = in_sizes[0] / (B * 3);  // x is (B, N, 3)

    float*  out   = (float*)d_out;
    double* acc   = (double*)d_ws;
    float*  stats = (float*)((char*)d_ws + 64);

    hipMemsetAsync(d_ws, 0, 64, stream);
    hipMemsetAsync(d_out, 0, (size_t)out_size * sizeof(float), stream);

    ea_reduce_kernel<<<256, 256, 0, stream>>>(ea, E, acc);
    finalize_stats_kernel<<<1, 1, 0, stream>>>(acc, E, stats);

    int eblocks = (E + 255) / 256;
    edge_kernel<<<eblocks, 256, 0, stream>>>(x, ei, ea, wmean, wstd,
                                             W1, b1, W2, b2, W3, stats, out, N, E);

    int oblocks = (out_size + 255) / 256;
    output_kernel<<<oblocks, 256, 0, stream>>>(out, b3, out_size);
}